// Round 16
// baseline (72.562 us; speedup 1.0000x reference)
//
#include <hip/hip_runtime.h>
#include <hip/hip_bf16.h>

typedef __attribute__((ext_vector_type(8))) __bf16 bf16x8;
typedef __attribute__((ext_vector_type(4))) float f32x4;
typedef __attribute__((ext_vector_type(4))) unsigned short u16x4;
typedef unsigned short u16;
typedef unsigned long long u64;

typedef __attribute__((address_space(1))) void gvoid;
typedef __attribute__((address_space(3))) void lvoid;

#define B_DIM 8192
#define MFMA(a, b, c) __builtin_amdgcn_mfma_f32_16x16x32_bf16((a), (b), (c), 0, 0, 0)

__device__ __forceinline__ u16x4 cvt4(f32x4 v) {
    u16x4 r;
    r.x = __builtin_bit_cast(u16, __float2bfloat16(v.x));
    r.y = __builtin_bit_cast(u16, __float2bfloat16(v.y));
    r.z = __builtin_bit_cast(u16, __float2bfloat16(v.z));
    r.w = __builtin_bit_cast(u16, __float2bfloat16(v.w));
    return r;
}

// R x 64 bf16 tile stage (256 threads). LDS dest linear (global_load_lds
// requirement); global SOURCE column pre-permuted so LDS slot s of row r holds
// global slot s^(r&7); readers apply the same XOR (ld_frag). [rule #21]
// Verified round-3: bank-conflict = 0.
template<int R>
__device__ __forceinline__ void stage_tile(const u16* g, int ldg, u16* ls, int t) {
#pragma unroll
    for (int it = 0; it < R / 32; ++it) {
        int e = it * 2048 + t * 8;
        int r = e >> 6;
        int slot = (e & 63) >> 3;
        int csrc = (slot ^ (r & 7)) << 3;
        __builtin_amdgcn_global_load_lds((gvoid*)(g + (size_t)r * ldg + csrc),
                                         (lvoid*)&ls[e], 16, 0, 0);
    }
}

__device__ __forceinline__ bf16x8 ld_frag(const u16* ls, int row, int kslot) {
    return *(const bf16x8*)&ls[row * 64 + ((kslot ^ (row & 7)) << 3)];
}

// ---------------- 1. gate dots + weight conversion + zero d0 slabs ----------------
__global__ void k_dots(const float* __restrict__ prev_b, const int* __restrict__ prev_depth,
                       const float* __restrict__ w_f,
                       const float* __restrict__ wa00f, const float* __restrict__ wa10f,
                       const float* __restrict__ wb00f, const float* __restrict__ wb11f,
                       const float* __restrict__ wb10f,
                       u16* __restrict__ wa00b, u16* __restrict__ wa10b,
                       u16* __restrict__ wb00b, u16* __restrict__ wb11b,
                       u16* __restrict__ wb10b,
                       float* __restrict__ dotv,
                       float* __restrict__ outA, float* __restrict__ outB) {
    int blk = blockIdx.x;
    if (blk >= 2048) {
        int t = (blk - 2048) * 256 + threadIdx.x;
        const int S = 131072, SB = 196608;
        const float* src; u16* dst; int off;
        if      (t < S)            { src = wa00f; dst = wa00b; off = t; }
        else if (t < 2 * S)        { src = wa10f; dst = wa10b; off = t - S; }
        else if (t < 2 * S + SB)   { src = wb00f; dst = wb00b; off = t - 2 * S; }
        else if (t < 3 * S + SB)   { src = wb11f; dst = wb11b; off = t - 2 * S - SB; }
        else if (t < 4 * S + SB)   { src = wb10f; dst = wb10b; off = t - 3 * S - SB; }
        else return;
        f32x4 v = *(const f32x4*)(src + (size_t)off * 4);
        *(u16x4*)(dst + (size_t)off * 4) = cvt4(v);
        return;
    }
    int wv = threadIdx.x >> 6, l = threadIdx.x & 63;
    int row = blk * 4 + wv;
    int depth = prev_depth[row];
    const float* bt = prev_b + (size_t)row * 1024 + (size_t)depth * 512;
    const int i1 = l * 4, i2 = 256 + l * 4;
    f32x4 v0 = *(const f32x4*)(bt + i1);
    f32x4 v1 = *(const f32x4*)(bt + i2);
    f32x4 w0 = *(const f32x4*)(w_f + i1);
    f32x4 w1 = *(const f32x4*)(w_f + i2);
    float dot = v0.x*w0.x + v0.y*w0.y + v0.z*w0.z + v0.w*w0.w
              + v1.x*w1.x + v1.y*w1.y + v1.z*w1.z + v1.w*w1.w;
    for (int off = 32; off > 0; off >>= 1) dot += __shfl_xor(dot, off, 64);
    size_t r1024 = (size_t)row * 1024;
    f32x4 z; z.x = 0.f; z.y = 0.f; z.z = 0.f; z.w = 0.f;
    *(f32x4*)(outA + r1024 + i1) = z;
    *(f32x4*)(outA + r1024 + i2) = z;
    *(f32x4*)(outB + r1024 + i1) = z;
    *(f32x4*)(outB + r1024 + i2) = z;
    if (l == 0) dotv[row] = dot;
}

// ---------------- 2. classify + wave-scan positions (2 barriers; verified r11-15) ----------
__global__ __launch_bounds__(1024) void k_scan(
        const float* __restrict__ dotv, const int* __restrict__ prev_depth,
        int* __restrict__ info, int* __restrict__ idx, int* __restrict__ cnt) {
    __shared__ u64 wtot[16];
    __shared__ int wany[16];
    const int tid = threadIdx.x, lane = tid & 63, wv = tid >> 6;
    int r0 = tid * 8;
    int dep[8]; float dv[8];
    int any = 0;
#pragma unroll
    for (int r = 0; r < 8; ++r) {
        dep[r] = prev_depth[r0 + r];
        dv[r] = dotv[r0 + r];
        any |= dep[r];
    }
    for (int off = 32; off > 0; off >>= 1) any |= __shfl_xor(any, off, 64);
    if (lane == 0) wany[wv] = any;
    __syncthreads();
    int ga = 0;
#pragma unroll
    for (int w = 0; w < 16; ++w) ga |= wany[w];
    int az = (ga == 0);

    int rcls[8], rf[8], rj[8], rnd[8];
    u64 pk = 0;
#pragma unroll
    for (int r = 0; r < 8; ++r) {
        float sg = 1.0f / (1.0f + expf(-dv[r]));
        int fi = (int)rintf(sg);           // 0/1, round-half-even = jnp.round
        int f = az ? 1 : fi;
        int j = az ? 0 : fi;
        int nd = dep[r] + f - j;
        int cls;
        if (nd == 1)     cls = f ? (j ? 2 : 1) : 0;
        else             cls = (nd < 1) ? 3 : 4;
        rcls[r] = cls; rf[r] = f; rj[r] = j; rnd[r] = nd;
        if (cls < 3) pk += 1ull << (cls * 21);
    }
    u64 own = pk;
    for (int off = 1; off < 64; off <<= 1) {
        u64 v = __shfl_up(pk, off, 64);
        if (lane >= off) pk += v;
    }
    if (lane == 63) wtot[wv] = pk;
    __syncthreads();
    u64 wbase = 0, tot = 0;
#pragma unroll
    for (int w = 0; w < 16; ++w) {
        u64 v = wtot[w];
        if (w < wv) wbase += v;
        tot += v;
    }
    u64 excl = wbase + pk - own;
    const u64 M21 = (1ull << 21) - 1;
    int tot0 = (int)(tot & M21), tot1 = (int)((tot >> 21) & M21), tot2 = (int)((tot >> 42) & M21);
    int base0 = 0;
    int base1 = (tot0 + 63) & ~63;
    int base2 = base1 + ((tot1 + 63) & ~63);
    int o0 = base0 + (int)(excl & M21);
    int o1 = base1 + (int)((excl >> 21) & M21);
    int o2 = base2 + (int)((excl >> 42) & M21);
#pragma unroll
    for (int r = 0; r < 8; ++r) {
        int row = r0 + r, cls = rcls[r], pos = 0;
        if (cls == 0)      { pos = o0++; idx[pos] = row; }
        else if (cls == 1) { pos = o1++; idx[pos] = row; }
        else if (cls == 2) { pos = o2++; idx[pos] = row; }
        info[row] = cls | (rf[r] << 3) | (rj[r] << 4) | (rnd[r] << 5) | (pos << 7);
    }
    // pad idx up to 64-aligned boundaries with row 0 (safe; epilogues skip pads)
    if (tid < 64) {
        int p0 = tot0 + tid;          if (p0 < base1) idx[p0] = 0;
        int p1 = base1 + tot1 + tid;  if (p1 < base2) idx[p1] = 0;
        int end2 = base2 + ((tot2 + 63) & ~63);
        int p2 = base2 + tot2 + tid;  if (p2 < end2) idx[p2] = 0;
    }
    if (tid == 0) {
        cnt[0] = tot0; cnt[1] = tot1; cnt[2] = tot2;
        cnt[4] = base0; cnt[5] = base1; cnt[6] = base2;
    }
}

// ---------------- 3. compaction: A_all[pos] = bf16([X[row] | second[row]]) --------
__global__ void k_mid(const float* __restrict__ X, const float* __restrict__ prev_a,
                      const float* __restrict__ prev_b,
                      const int* __restrict__ idx, const int* __restrict__ cnt,
                      u16* __restrict__ A_all) {
    int wv = threadIdx.x >> 6, l = threadIdx.x & 63;
    const int i1 = l * 4, i2 = 256 + l * 4;
    int p = (int)blockIdx.x * 4 + wv;
    int base1 = cnt[5], base2 = cnt[6];
    int end2 = base2 + ((cnt[2] + 63) & ~63);
    if (p >= end2) return;
    const float* sec = (p < base1) ? (prev_a + 512)
                     : (p < base2) ? prev_b
                                   : (prev_b + 512);
    int row = idx[p];
    size_t r512 = (size_t)row * 512, r1024 = (size_t)row * 1024;
    f32x4 xa = *(const f32x4*)(X + r512 + i1);
    f32x4 xb = *(const f32x4*)(X + r512 + i2);
    f32x4 sa = *(const f32x4*)(sec + r1024 + i1);
    f32x4 sb = *(const f32x4*)(sec + r1024 + i2);
    size_t pbase = (size_t)p * 1024;
    *(u16x4*)(A_all + pbase + i1)       = cvt4(xa);
    *(u16x4*)(A_all + pbase + i2)       = cvt4(xb);
    *(u16x4*)(A_all + pbase + 512 + i1) = cvt4(sa);
    *(u16x4*)(A_all + pbase + 512 + i2) = cvt4(sb);
}

// ---------------- 4. GEMM stage 1 (128-row M-tiles, dual-acc) + trivial blocks ----------
// M-tile 128 halves W L2/L3 re-reads vs 64 (W traffic = #M-tiles x W bytes).
// 4 waves each own 32 rows x 64 cols (wr=wv*32, acc[2][4]). Natural XCD mapping.
// Over-coverage rows past a class count read garbage A (finite, in-bounds);
// the lt0+lr>=cc guard skips all their writes.
__global__ __launch_bounds__(256, 4) void k_s1(
    const u16* __restrict__ A_all,
    const u16* __restrict__ wa00, const u16* __restrict__ wa10,
    const u16* __restrict__ wb00, const u16* __restrict__ wb11,
    const u16* __restrict__ wb10,
    const int* __restrict__ idx, const int* __restrict__ cnt, const int* __restrict__ info,
    const float* __restrict__ prev_a, const float* __restrict__ prev_b,
    u16* __restrict__ na1_all, float* __restrict__ part,
    float* __restrict__ outA, float* __restrict__ outB,
    float* __restrict__ outD, float* __restrict__ outF, float* __restrict__ outJ)
{
    __shared__ u16 lsA[8192], lsB0[4096], lsB1[4096];
    int blk = (int)blockIdx.x;
    if (blk >= 528) {
        int pb_ = blk - 528;
        int wv = threadIdx.x >> 6, l = threadIdx.x & 63;
        int row = pb_ * 4 + wv;
        int inf = info[row];
        int cls = inf & 7;
        size_t r1024 = (size_t)row * 1024;
        const int i1 = l * 4, i2 = 256 + l * 4;
        if (l == 0) {
            outD[row] = (float)((inf >> 5) & 3);
            outF[row] = (float)((inf >> 3) & 1);
            outJ[row] = (float)((inf >> 4) & 1);
        }
        if (cls == 2 || cls == 3) {          // next_a1 = pa
            f32x4 pa0 = *(const f32x4*)(prev_a + r1024 + 512 + i1);
            f32x4 pa1 = *(const f32x4*)(prev_a + r1024 + 512 + i2);
            *(f32x4*)(outA + r1024 + 512 + i1) = pa0;
            *(f32x4*)(outA + r1024 + 512 + i2) = pa1;
            if (cls == 3) {                  // next_b1 = pb1
                f32x4 q10 = *(const f32x4*)(prev_b + r1024 + 512 + i1);
                f32x4 q11 = *(const f32x4*)(prev_b + r1024 + 512 + i2);
                *(f32x4*)(outB + r1024 + 512 + i1) = q10;
                *(f32x4*)(outB + r1024 + 512 + i2) = q11;
            }
        } else if (cls == 4) {               // zero both
            f32x4 z; z.x = 0.f; z.y = 0.f; z.z = 0.f; z.w = 0.f;
            *(f32x4*)(outA + r1024 + 512 + i1) = z;
            *(f32x4*)(outA + r1024 + 512 + i2) = z;
            *(f32x4*)(outB + r1024 + 512 + i1) = z;
            *(f32x4*)(outB + r1024 + 512 + i2) = z;
        }
        return;
    }
    int c0 = cnt[0], c1 = cnt[1], c2 = cnt[2];
    int base0 = cnt[4], base1 = cnt[5], base2 = cnt[6];
    int t0 = (c0 + 127) >> 7, t1 = (c1 + 127) >> 7, t2 = (c2 + 127) >> 7;
    int T = blk >> 3, nt = blk & 7;
    int cls, mb, cc;
    const u16 *W0, *W1 = nullptr;
    int ldW1 = 0;
    if (T < t0)                { cls = 0; mb = base0 + T * 128; cc = c0; W0 = wa00; W1 = wb00; ldW1 = 1536; }
    else if (T < t0 + t1)      { T -= t0; cls = 1; mb = base1 + T * 128; cc = c1; W0 = wa10; W1 = wb10; ldW1 = 1024; }
    else if (T < t0 + t1 + t2) { T -= t0 + t1; cls = 2; mb = base2 + T * 128; cc = c2; W0 = wb11; }
    else return;
    const int t = threadIdx.x;
    const int n0 = nt * 64;
    const int lane = t & 63, wv = t >> 6;
    const int wr = wv * 32;
    const int fr = lane & 15, fq = lane >> 4;

    f32x4 acc0[2][4] = {}, acc1[2][4] = {};

    for (int kq = 0; kq < 16; ++kq) {
        int cb = kq * 64;
        stage_tile<128>(A_all + (size_t)mb * 1024 + cb, 1024, lsA, t);
        stage_tile<64>(W0 + (size_t)n0 * 1024 + cb, 1024, lsB0, t);
        bool dual = (cls == 0) || (cls == 1 && kq < 8);
        if (dual) stage_tile<64>(W1 + (size_t)n0 * ldW1 + cb, ldW1, lsB1, t);
        __syncthreads();
#pragma unroll
        for (int kk = 0; kk < 2; ++kk) {
            int ks = kk * 4 + fq;
            bf16x8 a[2], b0[4], b1[4];
#pragma unroll
            for (int mi = 0; mi < 2; ++mi) a[mi] = ld_frag(lsA, wr + mi * 16 + fr, ks);
#pragma unroll
            for (int ni = 0; ni < 4; ++ni) b0[ni] = ld_frag(lsB0, ni * 16 + fr, ks);
            if (dual) {
#pragma unroll
                for (int ni = 0; ni < 4; ++ni) b1[ni] = ld_frag(lsB1, ni * 16 + fr, ks);
            }
#pragma unroll
            for (int mi = 0; mi < 2; ++mi)
#pragma unroll
                for (int ni = 0; ni < 4; ++ni) {
                    acc0[mi][ni] = MFMA(a[mi], b0[ni], acc0[mi][ni]);
                    if (dual) acc1[mi][ni] = MFMA(a[mi], b1[ni], acc1[mi][ni]);
                }
        }
        __syncthreads();
    }
    int lt0 = T * 128;
#pragma unroll
    for (int mi = 0; mi < 2; ++mi)
#pragma unroll
        for (int jj = 0; jj < 4; ++jj) {
            int lr = wr + mi * 16 + fq * 4 + jj;
            if (lt0 + lr >= cc) continue;
            int grow = idx[mb + lr];
#pragma unroll
            for (int ni = 0; ni < 4; ++ni) {
                int col = n0 + ni * 16 + fr;
                float v = acc0[mi][ni][jj];
                if (cls < 2) {
                    na1_all[(size_t)(mb + lr) * 512 + col] = __builtin_bit_cast(u16, __float2bfloat16(v));
                    outA[(size_t)grow * 1024 + 512 + col] = v;
                    part[(size_t)(mb + lr) * 512 + col] = acc1[mi][ni][jj];
                } else {
                    outB[(size_t)grow * 1024 + 512 + col] = v;
                }
            }
        }
}

// ---------------- 5. GEMM stage 2: K=512 tail + partial init (128-row M-tiles) ----------
__global__ __launch_bounds__(256, 4) void k_s2(
    const u16* __restrict__ na1_all,
    const u16* __restrict__ wb00, const u16* __restrict__ wb10,
    const int* __restrict__ idx, const int* __restrict__ cnt,
    const float* __restrict__ part, float* __restrict__ outB)
{
    __shared__ u16 lsA[8192], lsB[4096];
    int c0 = cnt[0], c1 = cnt[1];
    int base0 = cnt[4], base1 = cnt[5];
    int t0 = (c0 + 127) >> 7, t1 = (c1 + 127) >> 7;
    int blk = (int)blockIdx.x;
    int T = blk >> 3, nt = blk & 7;
    int mb, cc, ldW, kofs;
    const u16* W;
    if (T < t0)           { mb = base0 + T * 128; cc = c0; W = wb00; ldW = 1536; kofs = 1024; }
    else if (T < t0 + t1) { T -= t0; mb = base1 + T * 128; cc = c1; W = wb10; ldW = 1024; kofs = 512; }
    else return;
    const int t = threadIdx.x;
    const int n0 = nt * 64;
    const int lane = t & 63, wv = t >> 6;
    const int wr = wv * 32;
    const int fr = lane & 15, fq = lane >> 4;

    f32x4 acc[2][4];
#pragma unroll
    for (int mi = 0; mi < 2; ++mi)
#pragma unroll
        for (int ni = 0; ni < 4; ++ni)
#pragma unroll
            for (int jj = 0; jj < 4; ++jj)
                acc[mi][ni][jj] = part[(size_t)(mb + wr + mi * 16 + fq * 4 + jj) * 512
                                       + n0 + ni * 16 + fr];

    for (int kq = 0; kq < 8; ++kq) {
        stage_tile<128>(na1_all + (size_t)mb * 512 + kq * 64, 512, lsA, t);
        stage_tile<64>(W + (size_t)n0 * ldW + kofs + kq * 64, ldW, lsB, t);
        __syncthreads();
#pragma unroll
        for (int kk = 0; kk < 2; ++kk) {
            int ks = kk * 4 + fq;
            bf16x8 a[2], b[4];
#pragma unroll
            for (int mi = 0; mi < 2; ++mi) a[mi] = ld_frag(lsA, wr + mi * 16 + fr, ks);
#pragma unroll
            for (int ni = 0; ni < 4; ++ni) b[ni] = ld_frag(lsB, ni * 16 + fr, ks);
#pragma unroll
            for (int mi = 0; mi < 2; ++mi)
#pragma unroll
                for (int ni = 0; ni < 4; ++ni)
                    acc[mi][ni] = MFMA(a[mi], b[ni], acc[mi][ni]);
        }
        __syncthreads();
    }
    int lt0 = T * 128;
#pragma unroll
    for (int mi = 0; mi < 2; ++mi)
#pragma unroll
        for (int jj = 0; jj < 4; ++jj) {
            int lr = wr + mi * 16 + fq * 4 + jj;
            if (lt0 + lr >= cc) continue;
            int grow = idx[mb + lr];
#pragma unroll
            for (int ni = 0; ni < 4; ++ni) {
                int col = n0 + ni * 16 + fr;
                outB[(size_t)grow * 1024 + 512 + col] = acc[mi][ni][jj];
            }
        }
}

extern "C" void kernel_launch(void* const* d_in, const int* in_sizes, int n_in,
                              void* d_out, int out_size, void* d_ws, size_t ws_size,
                              hipStream_t stream) {
    const float* X          = (const float*)d_in[0];
    const float* prev_a     = (const float*)d_in[1];
    const float* prev_b     = (const float*)d_in[2];
    const int*   prev_depth = (const int*)d_in[3];
    const float* w_f        = (const float*)d_in[4];
    const float* w_a00      = (const float*)d_in[5];
    const float* w_a10      = (const float*)d_in[6];
    const float* w_b00      = (const float*)d_in[7];
    const float* w_b11      = (const float*)d_in[8];
    const float* w_b10      = (const float*)d_in[9];

    float* out  = (float*)d_out;
    float* outA = out;
    float* outB = out + 8388608;
    float* outD = out + 16777216;
    float* outF = outD + 8192;
    float* outJ = outF + 8192;

    char* ws = (char*)d_ws;
    size_t off = 0;
    auto alloc = [&](size_t bytes) -> char* {
        char* p = ws + off;
        off += (bytes + 255) & ~(size_t)255;
        return p;
    };
    const int ROWS = 8576;   // 8192 + 128-tile coverage slack
    u16* A_all    = (u16*)alloc((size_t)ROWS * 1024 * 2);
    u16* na1_all  = (u16*)alloc((size_t)ROWS * 512 * 2);
    float* part   = (float*)alloc((size_t)ROWS * 512 * 4);
    u16* wa00b = (u16*)alloc((size_t)512 * 1024 * 2);
    u16* wa10b = (u16*)alloc((size_t)512 * 1024 * 2);
    u16* wb00b = (u16*)alloc((size_t)512 * 1536 * 2);
    u16* wb11b = (u16*)alloc((size_t)512 * 1024 * 2);
    u16* wb10b = (u16*)alloc((size_t)512 * 1024 * 2);
    float* dotv = (float*)alloc((size_t)B_DIM * 4);
    int* info   = (int*)alloc((size_t)B_DIM * 4);
    int* idx    = (int*)alloc((size_t)ROWS * 4);
    int* cnt    = (int*)alloc(256);
    if (off > ws_size) return;

    k_dots<<<4864, 256, 0, stream>>>(prev_b, prev_depth, w_f,
                                     w_a00, w_a10, w_b00, w_b11, w_b10,
                                     wa00b, wa10b, wb00b, wb11b, wb10b,
                                     dotv, outA, outB);
    k_scan<<<1, 1024, 0, stream>>>(dotv, prev_depth, info, idx, cnt);
    k_mid<<<2080, 256, 0, stream>>>(X, prev_a, prev_b, idx, cnt, A_all);
    k_s1<<<2576, 256, 0, stream>>>(A_all, wa00b, wa10b, wb00b, wb11b, wb10b,
                                   idx, cnt, info, prev_a, prev_b,
                                   na1_all, part, outA, outB, outD, outF, outJ);
    k_s2<<<528, 256, 0, stream>>>(na1_all, wb00b, wb10b, idx, cnt, part, outB);
}

// Round 17
// 63.559 us; speedup vs baseline: 1.1416x; 1.1416x over previous
//
#include <hip/hip_runtime.h>
#include <hip/hip_bf16.h>

typedef __attribute__((ext_vector_type(8))) __bf16 bf16x8;
typedef __attribute__((ext_vector_type(4))) float f32x4;
typedef __attribute__((ext_vector_type(4))) unsigned short u16x4;
typedef unsigned short u16;
typedef unsigned long long u64;

typedef __attribute__((address_space(1))) void gvoid;
typedef __attribute__((address_space(3))) void lvoid;

#define B_DIM 8192
#define MFMA(a, b, c) __builtin_amdgcn_mfma_f32_16x16x32_bf16((a), (b), (c), 0, 0, 0)
#define NT_STORE(p, v) __builtin_nontemporal_store((v), (p))

__device__ __forceinline__ u16x4 cvt4(f32x4 v) {
    u16x4 r;
    r.x = __builtin_bit_cast(u16, __float2bfloat16(v.x));
    r.y = __builtin_bit_cast(u16, __float2bfloat16(v.y));
    r.z = __builtin_bit_cast(u16, __float2bfloat16(v.z));
    r.w = __builtin_bit_cast(u16, __float2bfloat16(v.w));
    return r;
}

// 64x64 bf16 tile stage (256 threads, 2x16B each). LDS dest linear
// (global_load_lds requirement); global SOURCE column pre-permuted so LDS slot
// s of row r holds global slot s^(r&7); readers apply the same XOR (ld_frag).
// [rule #21 both-sides] Verified round-3: bank-conflict = 0.
__device__ __forceinline__ void stage64(const u16* g, int ldg, u16* ls, int t) {
#pragma unroll
    for (int it = 0; it < 2; ++it) {
        int e = it * 2048 + t * 8;
        int r = e >> 6;
        int slot = (e & 63) >> 3;
        int csrc = (slot ^ (r & 7)) << 3;
        __builtin_amdgcn_global_load_lds((gvoid*)(g + (size_t)r * ldg + csrc),
                                         (lvoid*)&ls[e], 16, 0, 0);
    }
}

__device__ __forceinline__ bf16x8 ld_frag(const u16* ls, int row, int kslot) {
    return *(const bf16x8*)&ls[row * 64 + ((kslot ^ (row & 7)) << 3)];
}

// ---------------- 1. gate dots + weight conversion + zero d0 slabs ----------------
__global__ void k_dots(const float* __restrict__ prev_b, const int* __restrict__ prev_depth,
                       const float* __restrict__ w_f,
                       const float* __restrict__ wa00f, const float* __restrict__ wa10f,
                       const float* __restrict__ wb00f, const float* __restrict__ wb11f,
                       const float* __restrict__ wb10f,
                       u16* __restrict__ wa00b, u16* __restrict__ wa10b,
                       u16* __restrict__ wb00b, u16* __restrict__ wb11b,
                       u16* __restrict__ wb10b,
                       float* __restrict__ dotv,
                       float* __restrict__ outA, float* __restrict__ outB) {
    int blk = blockIdx.x;
    if (blk >= 2048) {
        int t = (blk - 2048) * 256 + threadIdx.x;
        const int S = 131072, SB = 196608;
        const float* src; u16* dst; int off;
        if      (t < S)            { src = wa00f; dst = wa00b; off = t; }
        else if (t < 2 * S)        { src = wa10f; dst = wa10b; off = t - S; }
        else if (t < 2 * S + SB)   { src = wb00f; dst = wb00b; off = t - 2 * S; }
        else if (t < 3 * S + SB)   { src = wb11f; dst = wb11b; off = t - 2 * S - SB; }
        else if (t < 4 * S + SB)   { src = wb10f; dst = wb10b; off = t - 3 * S - SB; }
        else return;
        f32x4 v = *(const f32x4*)(src + (size_t)off * 4);
        *(u16x4*)(dst + (size_t)off * 4) = cvt4(v);
        return;
    }
    int wv = threadIdx.x >> 6, l = threadIdx.x & 63;
    int row = blk * 4 + wv;
    int depth = prev_depth[row];
    const float* bt = prev_b + (size_t)row * 1024 + (size_t)depth * 512;
    const int i1 = l * 4, i2 = 256 + l * 4;
    f32x4 v0 = *(const f32x4*)(bt + i1);
    f32x4 v1 = *(const f32x4*)(bt + i2);
    f32x4 w0 = *(const f32x4*)(w_f + i1);
    f32x4 w1 = *(const f32x4*)(w_f + i2);
    float dot = v0.x*w0.x + v0.y*w0.y + v0.z*w0.z + v0.w*w0.w
              + v1.x*w1.x + v1.y*w1.y + v1.z*w1.z + v1.w*w1.w;
    for (int off = 32; off > 0; off >>= 1) dot += __shfl_xor(dot, off, 64);
    size_t r1024 = (size_t)row * 1024;
    f32x4 z; z.x = 0.f; z.y = 0.f; z.z = 0.f; z.w = 0.f;
    NT_STORE((f32x4*)(outA + r1024 + i1), z);
    NT_STORE((f32x4*)(outA + r1024 + i2), z);
    NT_STORE((f32x4*)(outB + r1024 + i1), z);
    NT_STORE((f32x4*)(outB + r1024 + i2), z);
    if (l == 0) dotv[row] = dot;
}

// ---------------- 2. classify + wave-scan positions (2 barriers; verified r11-16) ----------
__global__ __launch_bounds__(1024) void k_scan(
        const float* __restrict__ dotv, const int* __restrict__ prev_depth,
        int* __restrict__ info, int* __restrict__ idx, int* __restrict__ cnt) {
    __shared__ u64 wtot[16];
    __shared__ int wany[16];
    const int tid = threadIdx.x, lane = tid & 63, wv = tid >> 6;
    int r0 = tid * 8;
    int dep[8]; float dv[8];
    int any = 0;
#pragma unroll
    for (int r = 0; r < 8; ++r) {
        dep[r] = prev_depth[r0 + r];
        dv[r] = dotv[r0 + r];
        any |= dep[r];
    }
    for (int off = 32; off > 0; off >>= 1) any |= __shfl_xor(any, off, 64);
    if (lane == 0) wany[wv] = any;
    __syncthreads();
    int ga = 0;
#pragma unroll
    for (int w = 0; w < 16; ++w) ga |= wany[w];
    int az = (ga == 0);

    int rcls[8], rf[8], rj[8], rnd[8];
    u64 pk = 0;
#pragma unroll
    for (int r = 0; r < 8; ++r) {
        float sg = 1.0f / (1.0f + expf(-dv[r]));
        int fi = (int)rintf(sg);           // 0/1, round-half-even = jnp.round
        int f = az ? 1 : fi;
        int j = az ? 0 : fi;
        int nd = dep[r] + f - j;
        int cls;
        if (nd == 1)     cls = f ? (j ? 2 : 1) : 0;
        else             cls = (nd < 1) ? 3 : 4;
        rcls[r] = cls; rf[r] = f; rj[r] = j; rnd[r] = nd;
        if (cls < 3) pk += 1ull << (cls * 21);
    }
    u64 own = pk;
    for (int off = 1; off < 64; off <<= 1) {
        u64 v = __shfl_up(pk, off, 64);
        if (lane >= off) pk += v;
    }
    if (lane == 63) wtot[wv] = pk;
    __syncthreads();
    u64 wbase = 0, tot = 0;
#pragma unroll
    for (int w = 0; w < 16; ++w) {
        u64 v = wtot[w];
        if (w < wv) wbase += v;
        tot += v;
    }
    u64 excl = wbase + pk - own;
    const u64 M21 = (1ull << 21) - 1;
    int tot0 = (int)(tot & M21), tot1 = (int)((tot >> 21) & M21), tot2 = (int)((tot >> 42) & M21);
    int base0 = 0;
    int base1 = (tot0 + 63) & ~63;
    int base2 = base1 + ((tot1 + 63) & ~63);
    int o0 = base0 + (int)(excl & M21);
    int o1 = base1 + (int)((excl >> 21) & M21);
    int o2 = base2 + (int)((excl >> 42) & M21);
#pragma unroll
    for (int r = 0; r < 8; ++r) {
        int row = r0 + r, cls = rcls[r], pos = 0;
        if (cls == 0)      { pos = o0++; idx[pos] = row; }
        else if (cls == 1) { pos = o1++; idx[pos] = row; }
        else if (cls == 2) { pos = o2++; idx[pos] = row; }
        info[row] = cls | (rf[r] << 3) | (rj[r] << 4) | (rnd[r] << 5) | (pos << 7);
    }
    // pad idx up to 64-aligned boundaries with row 0 (safe; epilogues skip pads)
    if (tid < 64) {
        int p0 = tot0 + tid;          if (p0 < base1) idx[p0] = 0;
        int p1 = base1 + tot1 + tid;  if (p1 < base2) idx[p1] = 0;
        int end2 = base2 + ((tot2 + 63) & ~63);
        int p2 = base2 + tot2 + tid;  if (p2 < end2) idx[p2] = 0;
    }
    if (tid == 0) {
        cnt[0] = tot0; cnt[1] = tot1; cnt[2] = tot2;
        cnt[4] = base0; cnt[5] = base1; cnt[6] = base2;
    }
}

// ---------------- 3. compaction: A_all[pos] = bf16([X[row] | second[row]]) --------
__global__ void k_mid(const float* __restrict__ X, const float* __restrict__ prev_a,
                      const float* __restrict__ prev_b,
                      const int* __restrict__ idx, const int* __restrict__ cnt,
                      u16* __restrict__ A_all) {
    int wv = threadIdx.x >> 6, l = threadIdx.x & 63;
    const int i1 = l * 4, i2 = 256 + l * 4;
    int p = (int)blockIdx.x * 4 + wv;
    int base1 = cnt[5], base2 = cnt[6];
    int end2 = base2 + ((cnt[2] + 63) & ~63);
    if (p >= end2) return;
    const float* sec = (p < base1) ? (prev_a + 512)
                     : (p < base2) ? prev_b
                                   : (prev_b + 512);
    int row = idx[p];
    size_t r512 = (size_t)row * 512, r1024 = (size_t)row * 1024;
    f32x4 xa = *(const f32x4*)(X + r512 + i1);
    f32x4 xb = *(const f32x4*)(X + r512 + i2);
    f32x4 sa = *(const f32x4*)(sec + r1024 + i1);
    f32x4 sb = *(const f32x4*)(sec + r1024 + i2);
    size_t pbase = (size_t)p * 1024;
    *(u16x4*)(A_all + pbase + i1)       = cvt4(xa);
    *(u16x4*)(A_all + pbase + i2)       = cvt4(xb);
    *(u16x4*)(A_all + pbase + 512 + i1) = cvt4(sa);
    *(u16x4*)(A_all + pbase + 512 + i2) = cvt4(sb);
}

// ---------------- 4. GEMM stage 1 (64-row M-tiles, dual-acc) + trivial blocks ----------
// r15-verified geometry: 512+ live GEMM blocks (2/CU) — r16's 128-row tiles
// halved live blocks to 1/CU and REGRESSED (s1 is barrier-bound, not W-bound).
__global__ __launch_bounds__(256, 4) void k_s1(
    const u16* __restrict__ A_all,
    const u16* __restrict__ wa00, const u16* __restrict__ wa10,
    const u16* __restrict__ wb00, const u16* __restrict__ wb11,
    const u16* __restrict__ wb10,
    const int* __restrict__ idx, const int* __restrict__ cnt, const int* __restrict__ info,
    const float* __restrict__ prev_a, const float* __restrict__ prev_b,
    u16* __restrict__ na1_all, float* __restrict__ part,
    float* __restrict__ outA, float* __restrict__ outB,
    float* __restrict__ outD, float* __restrict__ outF, float* __restrict__ outJ)
{
    __shared__ u16 lsA[4096], lsB0[4096], lsB1[4096];
    int blk = (int)blockIdx.x;
    if (blk >= 1040) {
        int pb_ = blk - 1040;
        int wv = threadIdx.x >> 6, l = threadIdx.x & 63;
        int row = pb_ * 4 + wv;
        int inf = info[row];
        int cls = inf & 7;
        size_t r1024 = (size_t)row * 1024;
        const int i1 = l * 4, i2 = 256 + l * 4;
        if (l == 0) {
            NT_STORE(&outD[row], (float)((inf >> 5) & 3));
            NT_STORE(&outF[row], (float)((inf >> 3) & 1));
            NT_STORE(&outJ[row], (float)((inf >> 4) & 1));
        }
        if (cls == 2 || cls == 3) {          // next_a1 = pa
            f32x4 pa0 = *(const f32x4*)(prev_a + r1024 + 512 + i1);
            f32x4 pa1 = *(const f32x4*)(prev_a + r1024 + 512 + i2);
            NT_STORE((f32x4*)(outA + r1024 + 512 + i1), pa0);
            NT_STORE((f32x4*)(outA + r1024 + 512 + i2), pa1);
            if (cls == 3) {                  // next_b1 = pb1
                f32x4 q10 = *(const f32x4*)(prev_b + r1024 + 512 + i1);
                f32x4 q11 = *(const f32x4*)(prev_b + r1024 + 512 + i2);
                NT_STORE((f32x4*)(outB + r1024 + 512 + i1), q10);
                NT_STORE((f32x4*)(outB + r1024 + 512 + i2), q11);
            }
        } else if (cls == 4) {               // zero both
            f32x4 z; z.x = 0.f; z.y = 0.f; z.z = 0.f; z.w = 0.f;
            NT_STORE((f32x4*)(outA + r1024 + 512 + i1), z);
            NT_STORE((f32x4*)(outA + r1024 + 512 + i2), z);
            NT_STORE((f32x4*)(outB + r1024 + 512 + i1), z);
            NT_STORE((f32x4*)(outB + r1024 + 512 + i2), z);
        }
        return;
    }
    int c0 = cnt[0], c1 = cnt[1], c2 = cnt[2];
    int base0 = cnt[4], base1 = cnt[5], base2 = cnt[6];
    int t0 = (c0 + 63) >> 6, t1 = (c1 + 63) >> 6, t2 = (c2 + 63) >> 6;
    int T = blk >> 3, nt = blk & 7;
    int cls, mb, cc;
    const u16 *W0, *W1 = nullptr;
    int ldW1 = 0;
    if (T < t0)                { cls = 0; mb = base0 + T * 64; cc = c0; W0 = wa00; W1 = wb00; ldW1 = 1536; }
    else if (T < t0 + t1)      { T -= t0; cls = 1; mb = base1 + T * 64; cc = c1; W0 = wa10; W1 = wb10; ldW1 = 1024; }
    else if (T < t0 + t1 + t2) { T -= t0 + t1; cls = 2; mb = base2 + T * 64; cc = c2; W0 = wb11; }
    else return;
    const int t = threadIdx.x;
    const int n0 = nt * 64;
    const int lane = t & 63, wv = t >> 6;
    const int wr = (wv >> 1) * 32, wc = (wv & 1) * 32;
    const int fr = lane & 15, fq = lane >> 4;

    f32x4 acc0[2][2] = {}, acc1[2][2] = {};

    for (int kq = 0; kq < 16; ++kq) {
        int cb = kq * 64;
        stage64(A_all + (size_t)mb * 1024 + cb, 1024, lsA, t);
        stage64(W0 + (size_t)n0 * 1024 + cb, 1024, lsB0, t);
        bool dual = (cls == 0) || (cls == 1 && kq < 8);
        if (dual) stage64(W1 + (size_t)n0 * ldW1 + cb, ldW1, lsB1, t);
        __syncthreads();
#pragma unroll
        for (int kk = 0; kk < 2; ++kk) {
            int ks = kk * 4 + fq;
            bf16x8 a[2], b0[2], b1[2];
#pragma unroll
            for (int mi = 0; mi < 2; ++mi) a[mi] = ld_frag(lsA, wr + mi * 16 + fr, ks);
#pragma unroll
            for (int ni = 0; ni < 2; ++ni) b0[ni] = ld_frag(lsB0, wc + ni * 16 + fr, ks);
            if (dual) {
#pragma unroll
                for (int ni = 0; ni < 2; ++ni) b1[ni] = ld_frag(lsB1, wc + ni * 16 + fr, ks);
            }
#pragma unroll
            for (int mi = 0; mi < 2; ++mi)
#pragma unroll
                for (int ni = 0; ni < 2; ++ni) {
                    acc0[mi][ni] = MFMA(a[mi], b0[ni], acc0[mi][ni]);
                    if (dual) acc1[mi][ni] = MFMA(a[mi], b1[ni], acc1[mi][ni]);
                }
        }
        __syncthreads();
    }
    int lt0 = T * 64;
#pragma unroll
    for (int mi = 0; mi < 2; ++mi)
#pragma unroll
        for (int jj = 0; jj < 4; ++jj) {
            int lr = wr + mi * 16 + fq * 4 + jj;
            if (lt0 + lr >= cc) continue;
            int grow = idx[mb + lr];
#pragma unroll
            for (int ni = 0; ni < 2; ++ni) {
                int col = n0 + wc + ni * 16 + fr;
                float v = acc0[mi][ni][jj];
                if (cls < 2) {
                    na1_all[(size_t)(mb + lr) * 512 + col] = __builtin_bit_cast(u16, __float2bfloat16(v));
                    NT_STORE(&outA[(size_t)grow * 1024 + 512 + col], v);
                    part[(size_t)(mb + lr) * 512 + col] = acc1[mi][ni][jj];
                } else {
                    NT_STORE(&outB[(size_t)grow * 1024 + 512 + col], v);
                }
            }
        }
}

// ---------------- 5. GEMM stage 2: K=512 tail + partial init (r7/r15-verified) ----------
__global__ __launch_bounds__(256, 4) void k_s2(
    const u16* __restrict__ na1_all,
    const u16* __restrict__ wb00, const u16* __restrict__ wb10,
    const int* __restrict__ idx, const int* __restrict__ cnt,
    const float* __restrict__ part, float* __restrict__ outB)
{
    __shared__ u16 lsA[4096], lsB[4096];
    int c0 = cnt[0], c1 = cnt[1];
    int base0 = cnt[4], base1 = cnt[5];
    int t0 = (c0 + 63) >> 6, t1 = (c1 + 63) >> 6;
    int blk = (int)blockIdx.x;
    int T = blk >> 3, nt = blk & 7;
    int mb, cc, ldW, kofs;
    const u16* W;
    if (T < t0)           { mb = base0 + T * 64; cc = c0; W = wb00; ldW = 1536; kofs = 1024; }
    else if (T < t0 + t1) { T -= t0; mb = base1 + T * 64; cc = c1; W = wb10; ldW = 1024; kofs = 512; }
    else return;
    const int t = threadIdx.x;
    const int n0 = nt * 64;
    const int lane = t & 63, wv = t >> 6;
    const int wr = (wv >> 1) * 32, wc = (wv & 1) * 32;
    const int fr = lane & 15, fq = lane >> 4;

    f32x4 acc[2][2];
#pragma unroll
    for (int mi = 0; mi < 2; ++mi)
#pragma unroll
        for (int ni = 0; ni < 2; ++ni)
#pragma unroll
            for (int jj = 0; jj < 4; ++jj)
                acc[mi][ni][jj] = part[(size_t)(mb + wr + mi * 16 + fq * 4 + jj) * 512
                                       + n0 + wc + ni * 16 + fr];

    for (int kq = 0; kq < 8; ++kq) {
        stage64(na1_all + (size_t)mb * 512 + kq * 64, 512, lsA, t);
        stage64(W + (size_t)n0 * ldW + kofs + kq * 64, ldW, lsB, t);
        __syncthreads();
#pragma unroll
        for (int kk = 0; kk < 2; ++kk) {
            int ks = kk * 4 + fq;
            bf16x8 a[2], b[2];
#pragma unroll
            for (int mi = 0; mi < 2; ++mi) a[mi] = ld_frag(lsA, wr + mi * 16 + fr, ks);
#pragma unroll
            for (int ni = 0; ni < 2; ++ni) b[ni] = ld_frag(lsB, wc + ni * 16 + fr, ks);
#pragma unroll
            for (int mi = 0; mi < 2; ++mi)
#pragma unroll
                for (int ni = 0; ni < 2; ++ni)
                    acc[mi][ni] = MFMA(a[mi], b[ni], acc[mi][ni]);
        }
        __syncthreads();
    }
    int lt0 = T * 64;
#pragma unroll
    for (int mi = 0; mi < 2; ++mi)
#pragma unroll
        for (int jj = 0; jj < 4; ++jj) {
            int lr = wr + mi * 16 + fq * 4 + jj;
            if (lt0 + lr >= cc) continue;
            int grow = idx[mb + lr];
#pragma unroll
            for (int ni = 0; ni < 2; ++ni) {
                int col = n0 + wc + ni * 16 + fr;
                NT_STORE(&outB[(size_t)grow * 1024 + 512 + col], acc[mi][ni][jj]);
            }
        }
}

extern "C" void kernel_launch(void* const* d_in, const int* in_sizes, int n_in,
                              void* d_out, int out_size, void* d_ws, size_t ws_size,
                              hipStream_t stream) {
    const float* X          = (const float*)d_in[0];
    const float* prev_a     = (const float*)d_in[1];
    const float* prev_b     = (const float*)d_in[2];
    const int*   prev_depth = (const int*)d_in[3];
    const float* w_f        = (const float*)d_in[4];
    const float* w_a00      = (const float*)d_in[5];
    const float* w_a10      = (const float*)d_in[6];
    const float* w_b00      = (const float*)d_in[7];
    const float* w_b11      = (const float*)d_in[8];
    const float* w_b10      = (const float*)d_in[9];

    float* out  = (float*)d_out;
    float* outA = out;
    float* outB = out + 8388608;
    float* outD = out + 16777216;
    float* outF = outD + 8192;
    float* outJ = outF + 8192;

    char* ws = (char*)d_ws;
    size_t off = 0;
    auto alloc = [&](size_t bytes) -> char* {
        char* p = ws + off;
        off += (bytes + 255) & ~(size_t)255;
        return p;
    };
    const int ROWS = 8448;   // 8192 + 2x64-alignment slack
    u16* A_all    = (u16*)alloc((size_t)ROWS * 1024 * 2);
    u16* na1_all  = (u16*)alloc((size_t)ROWS * 512 * 2);
    float* part   = (float*)alloc((size_t)ROWS * 512 * 4);
    u16* wa00b = (u16*)alloc((size_t)512 * 1024 * 2);
    u16* wa10b = (u16*)alloc((size_t)512 * 1024 * 2);
    u16* wb00b = (u16*)alloc((size_t)512 * 1536 * 2);
    u16* wb11b = (u16*)alloc((size_t)512 * 1024 * 2);
    u16* wb10b = (u16*)alloc((size_t)512 * 1024 * 2);
    float* dotv = (float*)alloc((size_t)B_DIM * 4);
    int* info   = (int*)alloc((size_t)B_DIM * 4);
    int* idx    = (int*)alloc((size_t)ROWS * 4);
    int* cnt    = (int*)alloc(256);
    if (off > ws_size) return;

    k_dots<<<4864, 256, 0, stream>>>(prev_b, prev_depth, w_f,
                                     w_a00, w_a10, w_b00, w_b11, w_b10,
                                     wa00b, wa10b, wb00b, wb11b, wb10b,
                                     dotv, outA, outB);
    k_scan<<<1, 1024, 0, stream>>>(dotv, prev_depth, info, idx, cnt);
    k_mid<<<2080, 256, 0, stream>>>(X, prev_a, prev_b, idx, cnt, A_all);
    k_s1<<<3088, 256, 0, stream>>>(A_all, wa00b, wa10b, wb00b, wb11b, wb10b,
                                   idx, cnt, info, prev_a, prev_b,
                                   na1_all, part, outA, outB, outD, outF, outJ);
    k_s2<<<1040, 256, 0, stream>>>(na1_all, wb00b, wb10b, idx, cnt, part, outB);
}